// Round 1
// baseline (39.477 us; speedup 1.0000x reference)
//
#include <hip/hip_runtime.h>
#include <math.h>

#define BLOCK 256
#define NWAVE (BLOCK / 64)

__device__ __forceinline__ float finlen(float b, float d) {
    float l = b - d;
    return isfinite(l) ? l : 0.0f;
}

// Block-level reduction of (s0,s1,s2 sums; m0 max). Result valid in thread 0.
__device__ __forceinline__ void block_reduce(float& s0, float& s1, float& s2, float& m0) {
    __shared__ float ls0[NWAVE], ls1[NWAVE], ls2[NWAVE], lm0[NWAVE];
    const int lane = threadIdx.x & 63;
    const int wid  = threadIdx.x >> 6;
    #pragma unroll
    for (int off = 32; off > 0; off >>= 1) {
        s0 += __shfl_down(s0, off);
        s1 += __shfl_down(s1, off);
        s2 += __shfl_down(s2, off);
        m0 = fmaxf(m0, __shfl_down(m0, off));
    }
    if (lane == 0) { ls0[wid] = s0; ls1[wid] = s1; ls2[wid] = s2; lm0[wid] = m0; }
    __syncthreads();
    if (threadIdx.x == 0) {
        #pragma unroll
        for (int w = 1; w < NWAVE; ++w) {
            s0 += ls0[w];
            s1 += ls1[w];
            s2 += ls2[w];
            m0 = fmaxf(m0, lm0[w]);
        }
    }
}

__device__ __forceinline__ void write_final(float* out, float s0, float s1, float s2, float m0) {
    const float top2 = m0 * m0;
    const float t01 = 1.0f - top2;
    const float t0  = s0 - top2;
    out[0] = t01 + t0 + s1 + s2;  // loss
    out[1] = t01;
    out[2] = t0;
    out[3] = s1;
    out[4] = s2;
}

__global__ __launch_bounds__(BLOCK) void pass1(
    const float* __restrict__ g0, const float* __restrict__ g1,
    const float* __restrict__ g2, float* __restrict__ part,
    int npairs, float* __restrict__ out, int finalize)
{
    const float4* a0 = (const float4*)g0;
    const float4* a1 = (const float4*)g1;
    const float4* a2 = (const float4*)g2;
    const long n4 = (long)(npairs >> 1);
    const long tid = (long)blockIdx.x * BLOCK + threadIdx.x;
    const long stride = (long)gridDim.x * BLOCK;

    float s0 = 0.0f, s1 = 0.0f, s2 = 0.0f, m0 = -INFINITY;

    for (long i = tid; i < n4; i += stride) {
        const float4 v = a0[i];
        const float la = finlen(v.x, v.y);
        const float lb = finlen(v.z, v.w);
        s0 += la * la + lb * lb;
        m0 = fmaxf(m0, fmaxf(la, lb));
    }
    for (long i = tid; i < n4; i += stride) {
        const float4 v = a1[i];
        const float la = finlen(v.x, v.y);
        const float lb = finlen(v.z, v.w);
        s1 += la * la + lb * lb;
    }
    for (long i = tid; i < n4; i += stride) {
        const float4 v = a2[i];
        const float la = finlen(v.x, v.y);
        const float lb = finlen(v.z, v.w);
        s2 += la * la + lb * lb;
    }
    // odd-pair tail (not hit for 8M bars, kept for generality)
    if (tid == 0 && (npairs & 1)) {
        const int j = npairs - 1;
        const float l0 = finlen(g0[2 * j], g0[2 * j + 1]);
        const float l1 = finlen(g1[2 * j], g1[2 * j + 1]);
        const float l2 = finlen(g2[2 * j], g2[2 * j + 1]);
        s0 += l0 * l0; s1 += l1 * l1; s2 += l2 * l2;
        m0 = fmaxf(m0, l0);
    }

    block_reduce(s0, s1, s2, m0);

    if (threadIdx.x == 0) {
        if (finalize) {
            write_final(out, s0, s1, s2, m0);
        } else {
            float* p = part + (size_t)blockIdx.x * 4;
            p[0] = s0; p[1] = s1; p[2] = s2; p[3] = m0;
        }
    }
}

__global__ __launch_bounds__(BLOCK) void pass2(
    const float* __restrict__ part, int nblocks, float* __restrict__ out)
{
    float s0 = 0.0f, s1 = 0.0f, s2 = 0.0f, m0 = -INFINITY;
    for (int i = threadIdx.x; i < nblocks; i += BLOCK) {
        const float* p = part + (size_t)i * 4;
        s0 += p[0];
        s1 += p[1];
        s2 += p[2];
        m0 = fmaxf(m0, p[3]);
    }
    block_reduce(s0, s1, s2, m0);
    if (threadIdx.x == 0) write_final(out, s0, s1, s2, m0);
}

extern "C" void kernel_launch(void* const* d_in, const int* in_sizes, int n_in,
                              void* d_out, int out_size, void* d_ws, size_t ws_size,
                              hipStream_t stream) {
    const float* g0 = (const float*)d_in[0];
    const float* g1 = (const float*)d_in[1];
    const float* g2 = (const float*)d_in[2];
    float* out = (float*)d_out;
    float* part = (float*)d_ws;

    const int npairs = in_sizes[0] / 2;  // 8M bars per diagram

    int nblocks = 2048;  // 256 CUs x 8 blocks, memory-bound sweet spot
    const size_t need = (size_t)nblocks * 4 * sizeof(float);
    if (ws_size < need) nblocks = (int)(ws_size / (4 * sizeof(float)));

    if (nblocks >= 2) {
        pass1<<<nblocks, BLOCK, 0, stream>>>(g0, g1, g2, part, npairs, nullptr, 0);
        pass2<<<1, BLOCK, 0, stream>>>(part, nblocks, out);
    } else {
        // ws too small for partials: single-block fused fallback
        pass1<<<1, BLOCK, 0, stream>>>(g0, g1, g2, nullptr, npairs, out, 1);
    }
}